// Round 1
// baseline (1395.264 us; speedup 1.0000x reference)
//
#include <hip/hip_runtime.h>
#include <math.h>

typedef __attribute__((ext_vector_type(8))) short bf16x8;
typedef __attribute__((ext_vector_type(4))) float f32x4;

#define NB 64
#define NP 196
#define ND 2048
#define NA 512
#define NH 512
#define NE 512
#define NV 10000
#define NT 19
#define NKX 3072
#define NROW (NB*NP)

__device__ __forceinline__ unsigned short f2bu(float f){
    unsigned int u; __builtin_memcpy(&u, &f, 4);
    u = (u + 0x7FFFu + ((u >> 16) & 1u)) >> 16;
    return (unsigned short)u;
}
__device__ __forceinline__ float b2f(short s){
    unsigned int u = ((unsigned int)(unsigned short)s) << 16;
    float f; __builtin_memcpy(&f, &u, 4); return f;
}
__device__ __forceinline__ float sigm(float x){ return 1.f/(1.f + __expf(-x)); }

// ---------------- setup kernels ----------------

__global__ void k_cast4(const float4* __restrict__ src, ushort4* __restrict__ dst, int n4){
    int stride = gridDim.x * blockDim.x;
    for (int i = blockIdx.x*blockDim.x + threadIdx.x; i < n4; i += stride){
        float4 v = src[i];
        ushort4 o = { f2bu(v.x), f2bu(v.y), f2bu(v.z), f2bu(v.w) };
        dst[i] = o;
    }
}

// wcat[j][0:2560]=W_ih[j], [2560:3072]=W_hh[j]
__global__ void k_wcat(const float* __restrict__ wih, const float* __restrict__ whh,
                       unsigned short* __restrict__ wcat){
    int j = blockIdx.x;
    int k = blockIdx.y*256 + threadIdx.x;
    float v = (k < 2560) ? wih[j*2560 + k] : whh[j*512 + (k - 2560)];
    wcat[j*NKX + k] = f2bu(v);
}

__global__ void k_mean(const float* __restrict__ feats, float* __restrict__ meanf){
    int b = blockIdx.y;
    int d = blockIdx.x*256 + threadIdx.x;
    float s = 0.f;
    for (int p = 0; p < NP; p++) s += feats[(b*NP + p)*ND + d];
    meanf[b*ND + d] = s * (1.f/196.f);
}

// h0 (->bf16 hbf) and c0 (->f32 cst)
__global__ void k_hc0(const float* __restrict__ meanf,
                      const float* __restrict__ hw, const float* __restrict__ hb,
                      const float* __restrict__ cw, const float* __restrict__ cb,
                      unsigned short* __restrict__ hbf, float* __restrict__ cst){
    int sel = blockIdx.y;
    const float* wmat = sel ? cw : hw;
    const float* bias = sel ? cb : hb;
    int jg = blockIdx.x;
    int tid = threadIdx.x;
    int b = tid & 63, jj = tid >> 6;
    int j = jg*4 + jj;
    __shared__ float ml[64][33];
    __shared__ float wl[4][32];
    float acc = 0.f;
    for (int kc = 0; kc < ND; kc += 32){
        __syncthreads();
        #pragma unroll
        for (int q = 0; q < 8; q++){
            int lin = tid + q*256;
            int r = lin >> 5, kk = lin & 31;
            ml[r][kk] = meanf[r*ND + kc + kk];
        }
        if (tid < 128){ int r = tid >> 5, kk = tid & 31; wl[r][kk] = wmat[(jg*4 + r)*ND + kc + kk]; }
        __syncthreads();
        #pragma unroll
        for (int kk = 0; kk < 32; kk++) acc += ml[b][kk] * wl[jj][kk];
    }
    acc += bias[j];
    if (sel) cst[b*NH + j] = acc;
    else     hbf[b*NH + j] = f2bu(acc);
}

// att1 = feats(bf16) @ enc_w(bf16)^T + enc_b -> bf16 [12544][512]
__global__ void k_att1(const unsigned short* __restrict__ fbf,
                       const unsigned short* __restrict__ encw,
                       const float* __restrict__ enc_b,
                       unsigned short* __restrict__ att1){
    int w = threadIdx.x >> 6, l = threadIdx.x & 63;
    int mtile = blockIdx.x*4 + w;          // 0..783
    int ng = blockIdx.y;                   // 0..7
    int row = mtile*16 + (l & 15);
    int kg = (l >> 4) * 8;
    int colbase = ng*64 + (l & 15);
    f32x4 acc[4] = {};
    const unsigned short* arow = fbf + row*ND;
    for (int k0 = 0; k0 < ND; k0 += 32){
        bf16x8 af = *(const bf16x8*)(arow + k0 + kg);
        #pragma unroll
        for (int ni = 0; ni < 4; ni++){
            int col = colbase + ni*16;
            bf16x8 bv = *(const bf16x8*)(encw + col*ND + k0 + kg);
            acc[ni] = __builtin_amdgcn_mfma_f32_16x16x32_bf16(af, bv, acc[ni], 0, 0, 0);
        }
    }
    int r0 = mtile*16 + (l >> 4)*4;
    #pragma unroll
    for (int ni = 0; ni < 4; ni++){
        int col = ng*64 + ni*16 + (l & 15);
        float eb = enc_b[col];
        #pragma unroll
        for (int r = 0; r < 4; r++)
            att1[(r0 + r)*NA + col] = f2bu(acc[ni][r] + eb);
    }
}

// ---------------- per-step kernels ----------------

// hp[b][0:512] = h@dec_w^T ; hp[b][512:2560] = h@f_beta_w^T  (biases added later)
__global__ void k_hproj(const unsigned short* __restrict__ hbf,
                        const unsigned short* __restrict__ hwb,
                        float* __restrict__ hp){
    int w = threadIdx.x >> 6, l = threadIdx.x & 63;
    int nt = blockIdx.x;                   // 0..159
    int row = 16*w + (l & 15);
    int col = nt*16 + (l & 15);
    int kg = (l >> 4) * 8;
    f32x4 acc = {};
    for (int k0 = 0; k0 < NH; k0 += 32){
        bf16x8 af = *(const bf16x8*)(hbf + row*NH + k0 + kg);
        bf16x8 bv = *(const bf16x8*)(hwb + col*NH + k0 + kg);
        acc = __builtin_amdgcn_mfma_f32_16x16x32_bf16(af, bv, acc, 0, 0, 0);
    }
    int r0 = 16*w + (l >> 4)*4;
    #pragma unroll
    for (int r = 0; r < 4; r++)
        hp[(r0 + r)*2560 + col] = acc[r];
}

// e scores; also (pc==0) fill xh emb part + h part
__global__ void k_e(const unsigned short* __restrict__ att1,
                    const float* __restrict__ hp, const float* __restrict__ dec_b,
                    const float* __restrict__ att_w, const float* __restrict__ att_b,
                    const float* __restrict__ emb, const int* __restrict__ captions,
                    const unsigned short* __restrict__ hbf,
                    unsigned short* __restrict__ xh, float* __restrict__ ews, int t){
    __shared__ float at2[NA];
    __shared__ float aw[NA];
    int b = blockIdx.x >> 2, pc = blockIdx.x & 3;
    int tid = threadIdx.x;
    for (int j = tid; j < NA; j += 256){
        at2[j] = hp[b*2560 + j] + dec_b[j];
        aw[j]  = att_w[j];
    }
    if (pc == 0){
        int cap = captions[b*20 + t];
        for (int k = tid; k < NE; k += 256) xh[b*NKX + k] = f2bu(emb[cap*NE + k]);
        for (int j = tid; j < NH; j += 256) xh[b*NKX + 2560 + j] = hbf[b*NH + j];
    }
    __syncthreads();
    int pl = tid >> 2, q = tid & 3;
    if (pl < 49){
        int p = pc*49 + pl;
        const unsigned short* arow = att1 + (b*NP + p)*NA + q*128;
        float s = 0.f;
        for (int a0 = 0; a0 < 128; a0 += 8){
            bf16x8 v = *(const bf16x8*)(arow + a0);
            #pragma unroll
            for (int e = 0; e < 8; e++){
                int a = q*128 + a0 + e;
                float x = b2f(v[e]) + at2[a];
                s += fmaxf(x, 0.f) * aw[a];
            }
        }
        s += __shfl_xor(s, 1);
        s += __shfl_xor(s, 2);
        if (q == 0) ews[b*NP + p] = s + att_b[0];
    }
}

// softmax(e) per b (redundant per dchunk), awe = alpha@feats, gate*awe -> xh; alphas out
__global__ void k_awe(const float* __restrict__ ews, const unsigned short* __restrict__ fbf,
                      const float* __restrict__ hp, const float* __restrict__ f_beta_b,
                      const int* __restrict__ lengths,
                      unsigned short* __restrict__ xh, float* __restrict__ alphas_out, int t){
    __shared__ float al[NP];
    __shared__ float red[256];
    int dc = blockIdx.x;   // 0..7
    int b  = blockIdx.y;   // 0..63
    int tid = threadIdx.x;
    float v = (tid < NP) ? ews[b*NP + tid] : -1e30f;
    red[tid] = v; __syncthreads();
    for (int s = 128; s > 0; s >>= 1){ if (tid < s) red[tid] = fmaxf(red[tid], red[tid+s]); __syncthreads(); }
    float m = red[0]; __syncthreads();
    float ev = (tid < NP) ? __expf(v - m) : 0.f;
    red[tid] = ev; __syncthreads();
    for (int s = 128; s > 0; s >>= 1){ if (tid < s) red[tid] += red[tid+s]; __syncthreads(); }
    float inv = 1.f / red[0];
    if (tid < NP) al[tid] = ev * inv;
    __syncthreads();
    if (dc == 0 && tid < NP){
        int active = t < (lengths[b] - 1);
        alphas_out[(b*NT + t)*NP + tid] = active ? al[tid] : 0.f;
    }
    int d = dc*256 + tid;
    const unsigned short* fb = fbf + (b*NP)*ND + d;
    float acc = 0.f;
    #pragma unroll 4
    for (int p = 0; p < NP; p++) acc += al[p] * b2f(fb[p*ND]);
    float g = sigm(hp[b*2560 + 512 + d] + f_beta_b[d]);
    xh[b*NKX + 512 + d] = f2bu(g * acc);
}

// gates partials: part[s][b][j] = sum over k in [s*384,(s+1)*384) of xh[b][k]*wcat[j][k]
__global__ void k_gates(const unsigned short* __restrict__ xh,
                        const unsigned short* __restrict__ wcat,
                        float* __restrict__ part){
    int w = threadIdx.x >> 6, l = threadIdx.x & 63;
    int nt = blockIdx.x;   // 0..127
    int s  = blockIdx.y;   // 0..7
    int row = 16*w + (l & 15);
    int col = nt*16 + (l & 15);
    int kg = (l >> 4) * 8;
    int kbase = s*384;
    f32x4 acc = {};
    for (int k0 = 0; k0 < 384; k0 += 32){
        bf16x8 af = *(const bf16x8*)(xh + row*NKX + kbase + k0 + kg);
        bf16x8 bv = *(const bf16x8*)(wcat + col*NKX + kbase + k0 + kg);
        acc = __builtin_amdgcn_mfma_f32_16x16x32_bf16(af, bv, acc, 0, 0, 0);
    }
    int r0 = 16*w + (l >> 4)*4;
    #pragma unroll
    for (int r = 0; r < 4; r++)
        part[(s*64 + r0 + r)*2048 + col] = acc[r];
}

// LSTM pointwise for step t-1 (t in 1..19)
__global__ void k_lstm(const float* __restrict__ part,
                       const float* __restrict__ b_ih, const float* __restrict__ b_hh,
                       float* __restrict__ cst, unsigned short* __restrict__ hbf,
                       unsigned short* __restrict__ hsb, int t){
    int idx = blockIdx.x*256 + threadIdx.x;
    int b = idx >> 9, j = idx & 511;
    float gi = b_ih[j]        + b_hh[j];
    float gf = b_ih[512 + j]  + b_hh[512 + j];
    float gg = b_ih[1024 + j] + b_hh[1024 + j];
    float go = b_ih[1536 + j] + b_hh[1536 + j];
    #pragma unroll
    for (int s = 0; s < 8; s++){
        const float* pb = part + (s*64 + b)*2048;
        gi += pb[j]; gf += pb[512 + j]; gg += pb[1024 + j]; go += pb[1536 + j];
    }
    float c = cst[b*NH + j];
    float c2 = sigm(gf)*c + sigm(gi)*tanhf(gg);
    float h2 = sigm(go)*tanhf(c2);
    cst[b*NH + j] = c2;
    unsigned short hb16 = f2bu(h2);
    hbf[b*NH + j] = hb16;
    hsb[((t - 1)*64 + b)*NH + j] = hb16;
}

// Y = Hs(bf16) @ cls_w(bf16)^T + cls_b, masked -> out (B,T,V)
__global__ void k_cls(const unsigned short* __restrict__ hsb,
                      const unsigned short* __restrict__ clsw,
                      const float* __restrict__ cls_b,
                      const int* __restrict__ lengths,
                      float* __restrict__ yout){
    int w = threadIdx.x >> 6, l = threadIdx.x & 63;
    int id = blockIdx.x*4 + w;
    if (id >= 19*157) return;
    int mg = id / 157, ng = id % 157;
    int kg = (l >> 4) * 8;
    f32x4 acc[4][4] = {};
    for (int k0 = 0; k0 < NH; k0 += 32){
        bf16x8 am[4];
        #pragma unroll
        for (int mi = 0; mi < 4; mi++)
            am[mi] = *(const bf16x8*)(hsb + (mg*64 + mi*16 + (l & 15))*NH + k0 + kg);
        #pragma unroll
        for (int ni = 0; ni < 4; ni++){
            int ntile = ng*4 + ni;
            int colc = (ntile < 625 ? ntile : 624)*16 + (l & 15);
            bf16x8 bv = *(const bf16x8*)(clsw + colc*NH + k0 + kg);
            #pragma unroll
            for (int mi = 0; mi < 4; mi++)
                acc[mi][ni] = __builtin_amdgcn_mfma_f32_16x16x32_bf16(am[mi], bv, acc[mi][ni], 0, 0, 0);
        }
    }
    int t = mg;
    #pragma unroll
    for (int ni = 0; ni < 4; ni++){
        int ntile = ng*4 + ni;
        if (ntile >= 625) continue;
        int col = ntile*16 + (l & 15);
        float cb = cls_b[col];
        #pragma unroll
        for (int mi = 0; mi < 4; mi++){
            int rbase = mi*16 + (l >> 4)*4;
            #pragma unroll
            for (int r = 0; r < 4; r++){
                int bb = rbase + r;               // row within 64 = batch index
                int active = t < (lengths[bb] - 1);
                yout[(bb*NT + t)*NV + col] = active ? (acc[mi][ni][r] + cb) : 0.f;
            }
        }
    }
}

// ---------------- launch ----------------

extern "C" void kernel_launch(void* const* d_in, const int* in_sizes, int n_in,
                              void* d_out, int out_size, void* d_ws, size_t ws_size,
                              hipStream_t stream){
    const float* features = (const float*)d_in[0];
    const int*   captions = (const int*)d_in[1];
    const int*   lengths  = (const int*)d_in[2];
    const float* emb      = (const float*)d_in[3];
    const float* W_ih     = (const float*)d_in[4];
    const float* b_ih     = (const float*)d_in[5];
    const float* W_hh     = (const float*)d_in[6];
    const float* b_hh     = (const float*)d_in[7];
    const float* h_fc_w   = (const float*)d_in[8];
    const float* h_fc_b   = (const float*)d_in[9];
    const float* c_fc_w   = (const float*)d_in[10];
    const float* c_fc_b   = (const float*)d_in[11];
    const float* f_beta_w = (const float*)d_in[12];
    const float* f_beta_b = (const float*)d_in[13];
    const float* cls_w    = (const float*)d_in[14];
    const float* cls_b    = (const float*)d_in[15];
    const float* enc_w    = (const float*)d_in[16];
    const float* enc_b    = (const float*)d_in[17];
    const float* dec_w    = (const float*)d_in[18];
    const float* dec_b    = (const float*)d_in[19];
    const float* att_w    = (const float*)d_in[20];
    const float* att_b    = (const float*)d_in[21];

    char* w = (char*)d_ws;
    size_t off = 0;
    auto alloc = [&](size_t bytes)->char*{
        char* p = w + off;
        off += (bytes + 255) & ~(size_t)255;
        return p;
    };
    unsigned short* fbf   = (unsigned short*)alloc((size_t)NROW*ND*2);
    unsigned short* att1  = (unsigned short*)alloc((size_t)NROW*NA*2);
    unsigned short* encwb = (unsigned short*)alloc((size_t)NA*ND*2);
    unsigned short* hwb   = (unsigned short*)alloc((size_t)2560*NH*2);
    unsigned short* wcat  = (unsigned short*)alloc((size_t)2048*NKX*2);
    unsigned short* clswb = (unsigned short*)alloc((size_t)NV*NH*2);
    unsigned short* hsb   = (unsigned short*)alloc((size_t)NT*64*NH*2);
    unsigned short* hbf   = (unsigned short*)alloc((size_t)64*NH*2);
    unsigned short* xh    = (unsigned short*)alloc((size_t)64*NKX*2);
    float* meanf = (float*)alloc((size_t)64*ND*4);
    float* cst   = (float*)alloc((size_t)64*NH*4);
    float* hp    = (float*)alloc((size_t)64*2560*4);
    float* ews   = (float*)alloc((size_t)64*NP*4);
    float* part  = (float*)alloc((size_t)8*64*2048*4);

    float* yout = (float*)d_out;
    float* alphas_out = yout + (size_t)NB*NT*NV;

    // setup
    k_cast4<<<4096, 256, 0, stream>>>((const float4*)features, (ushort4*)fbf, NROW*ND/4);
    k_cast4<<<1024, 256, 0, stream>>>((const float4*)enc_w, (ushort4*)encwb, NA*ND/4);
    k_cast4<<<256, 256, 0, stream>>>((const float4*)dec_w, (ushort4*)hwb, 512*512/4);
    k_cast4<<<1024, 256, 0, stream>>>((const float4*)f_beta_w, (ushort4*)(hwb + 512*512), 2048*512/4);
    k_wcat<<<dim3(2048, 12), 256, 0, stream>>>(W_ih, W_hh, wcat);
    k_cast4<<<1024, 256, 0, stream>>>((const float4*)cls_w, (ushort4*)clswb, NV*NH/4);
    k_mean<<<dim3(8, 64), 256, 0, stream>>>(features, meanf);
    k_hc0<<<dim3(128, 2), 256, 0, stream>>>(meanf, h_fc_w, h_fc_b, c_fc_w, c_fc_b, hbf, cst);
    k_att1<<<dim3(196, 8), 256, 0, stream>>>(fbf, encwb, enc_b, att1);

    for (int t = 0; t < NT; t++){
        if (t > 0)
            k_lstm<<<128, 256, 0, stream>>>(part, b_ih, b_hh, cst, hbf, hsb, t);
        k_hproj<<<160, 256, 0, stream>>>(hbf, hwb, hp);
        k_e<<<256, 256, 0, stream>>>(att1, hp, dec_b, att_w, att_b, emb, captions, hbf, xh, ews, t);
        k_awe<<<dim3(8, 64), 256, 0, stream>>>(ews, fbf, hp, f_beta_b, lengths, xh, alphas_out, t);
        k_gates<<<dim3(128, 8), 256, 0, stream>>>(xh, wcat, part);
    }
    k_lstm<<<128, 256, 0, stream>>>(part, b_ih, b_hh, cst, hbf, hsb, NT);
    k_cls<<<746, 256, 0, stream>>>(hsb, clswb, cls_b, lengths, yout);
}

// Round 2
// 1235.932 us; speedup vs baseline: 1.1289x; 1.1289x over previous
//
#include <hip/hip_runtime.h>
#include <math.h>

typedef __attribute__((ext_vector_type(8))) short bf16x8;
typedef __attribute__((ext_vector_type(8))) unsigned short u16x8;
typedef __attribute__((ext_vector_type(4))) float f32x4;

#define NB 64
#define NP 196
#define ND 2048
#define NA 512
#define NH 512
#define NE 512
#define NV 10000
#define NT 19
#define NKX 3072
#define NROW (NB*NP)
#define NVP 10112          // padded vocab (79*128)
#define MROW 1280          // padded hsb rows (10*128)
#define PP 200             // padded p-dim for ftr

__device__ __forceinline__ unsigned short f2bu(float f){
    unsigned int u; __builtin_memcpy(&u, &f, 4);
    u = (u + 0x7FFFu + ((u >> 16) & 1u)) >> 16;
    return (unsigned short)u;
}
__device__ __forceinline__ float b2f(short s){
    unsigned int u = ((unsigned int)(unsigned short)s) << 16;
    float f; __builtin_memcpy(&f, &u, 4); return f;
}
__device__ __forceinline__ float sigm(float x){ return 1.f/(1.f + __expf(-x)); }

__device__ __forceinline__ void gll16(const void* g, void* l){
    __builtin_amdgcn_global_load_lds(
        (const __attribute__((address_space(1))) void*)g,
        (__attribute__((address_space(3))) void*)l, 16, 0, 0);
}

// ---------------- setup kernels ----------------

__global__ void k_cast4(const float4* __restrict__ src, ushort4* __restrict__ dst, int n4){
    int stride = gridDim.x * blockDim.x;
    for (int i = blockIdx.x*blockDim.x + threadIdx.x; i < n4; i += stride){
        float4 v = src[i];
        ushort4 o = { f2bu(v.x), f2bu(v.y), f2bu(v.z), f2bu(v.w) };
        dst[i] = o;
    }
}

// wcat[j][0:2560]=W_ih[j], [2560:3072]=W_hh[j]
__global__ void k_wcat(const float* __restrict__ wih, const float* __restrict__ whh,
                       unsigned short* __restrict__ wcat){
    int j = blockIdx.x;
    int k = blockIdx.y*256 + threadIdx.x;
    float v = (k < 2560) ? wih[j*2560 + k] : whh[j*512 + (k - 2560)];
    wcat[j*NKX + k] = f2bu(v);
}

// feats (f32, [b][p][d]) -> fbf bf16 [b*p][d], ftr bf16 [b][d][PP] (pad 0), meanf f32 [b][d]
__global__ void k_tr(const float* __restrict__ feats,
                     unsigned short* __restrict__ fbf,
                     unsigned short* __restrict__ ftr,
                     float* __restrict__ meanf){
    __shared__ unsigned short sm[64][202];
    __shared__ float rsum[256];
    int dt = blockIdx.x;     // 0..31 (64-d tile)
    int b  = blockIdx.y;     // 0..63
    int tid = threadIdx.x;
    int d = tid & 63;
    int gd = dt*64 + d;
    float s = 0.f;
    for (int p = (tid >> 6); p < NP; p += 4){
        float v = feats[((size_t)(b*NP + p))*ND + gd];
        unsigned short u = f2bu(v);
        fbf[((size_t)(b*NP + p))*ND + gd] = u;
        sm[d][p] = u;
        s += v;
    }
    rsum[tid] = s;
    __syncthreads();
    if (tid < 64)
        meanf[b*ND + dt*64 + tid] =
            (rsum[tid] + rsum[tid+64] + rsum[tid+128] + rsum[tid+192]) * (1.f/196.f);
    for (int v = tid; v < 64*25; v += 256){
        int r = v/25, c = v - r*25;
        u16x8 o;
        #pragma unroll
        for (int j = 0; j < 8; j++){ int p = c*8 + j; o[j] = (p < NP) ? sm[r][p] : (unsigned short)0; }
        *(u16x8*)(ftr + ((size_t)(b*ND + dt*64 + r))*PP + c*8) = o;
    }
}

// h0 (->bf16 hbf) and c0 (->f32 cst)
__global__ void k_hc0(const float* __restrict__ meanf,
                      const float* __restrict__ hw, const float* __restrict__ hb,
                      const float* __restrict__ cw, const float* __restrict__ cb,
                      unsigned short* __restrict__ hbf, float* __restrict__ cst){
    int sel = blockIdx.y;
    const float* wmat = sel ? cw : hw;
    const float* bias = sel ? cb : hb;
    int jg = blockIdx.x;
    int tid = threadIdx.x;
    int b = tid & 63, jj = tid >> 6;
    int j = jg*4 + jj;
    __shared__ float ml[64][33];
    __shared__ float wl[4][32];
    float acc = 0.f;
    for (int kc = 0; kc < ND; kc += 32){
        __syncthreads();
        #pragma unroll
        for (int q = 0; q < 8; q++){
            int lin = tid + q*256;
            int r = lin >> 5, kk = lin & 31;
            ml[r][kk] = meanf[r*ND + kc + kk];
        }
        if (tid < 128){ int r = tid >> 5, kk = tid & 31; wl[r][kk] = wmat[(jg*4 + r)*ND + kc + kk]; }
        __syncthreads();
        #pragma unroll
        for (int kk = 0; kk < 32; kk++) acc += ml[b][kk] * wl[jj][kk];
    }
    acc += bias[j];
    if (sel) cst[b*NH + j] = acc;
    else     hbf[b*NH + j] = f2bu(acc);
}

// ---------------- 128x128-tile GEMM core (m97 structure) ----------------
// C[128x128] tile at (brow,bcol); A[M][K], B[N][K] row-major bf16, both B^T-style operands.
template<int K>
__device__ __forceinline__ void gemm128(const unsigned short* __restrict__ A,
                                        const unsigned short* __restrict__ B,
                                        int brow, int bcol, f32x4 acc[4][4]){
    __shared__ unsigned short As[128*32];
    __shared__ unsigned short Bs[128*32];
    int tid = threadIdx.x;
    int w = tid >> 6, l = tid & 63;
    int wr = (w >> 1) * 64, wc = (w & 1) * 64;
    int lr = l & 15, kg = (l >> 4) * 8;
    const unsigned short* ga0 = A + (size_t)(brow + (tid >> 2))*K + (tid & 3)*8;
    const unsigned short* gb0 = B + (size_t)(bcol + (tid >> 2))*K + (tid & 3)*8;
    for (int k0 = 0; k0 < K; k0 += 32){
        __syncthreads();
        gll16(ga0 + k0,            As + w*512);
        gll16(ga0 + (size_t)64*K + k0, As + 2048 + w*512);
        gll16(gb0 + k0,            Bs + w*512);
        gll16(gb0 + (size_t)64*K + k0, Bs + 2048 + w*512);
        __syncthreads();
        bf16x8 af[4], bfr[4];
        #pragma unroll
        for (int mi = 0; mi < 4; mi++)
            af[mi] = *(const bf16x8*)(As + (wr + mi*16 + lr)*32 + kg);
        #pragma unroll
        for (int ni = 0; ni < 4; ni++)
            bfr[ni] = *(const bf16x8*)(Bs + (wc + ni*16 + lr)*32 + kg);
        #pragma unroll
        for (int ni = 0; ni < 4; ni++){
            #pragma unroll
            for (int mi = 0; mi < 4; mi++)
                acc[mi][ni] = __builtin_amdgcn_mfma_f32_16x16x32_bf16(af[mi], bfr[ni], acc[mi][ni], 0, 0, 0);
        }
    }
}

// att1 = fbf @ encw^T + enc_b -> bf16 [12544][512]
__global__ void k_gemm_att1(const unsigned short* __restrict__ fbf,
                            const unsigned short* __restrict__ encw,
                            const float* __restrict__ enc_b,
                            unsigned short* __restrict__ att1){
    f32x4 acc[4][4] = {};
    int brow = blockIdx.x*128, bcol = blockIdx.y*128;
    gemm128<ND>(fbf, encw, brow, bcol, acc);
    int w = threadIdx.x >> 6, l = threadIdx.x & 63;
    int wr = (w >> 1) * 64, wc = (w & 1) * 64;
    int r0 = brow + wr + (l >> 4)*4;
    int c0 = bcol + wc + (l & 15);
    #pragma unroll
    for (int ni = 0; ni < 4; ni++){
        int col = c0 + ni*16;
        float eb = enc_b[col];
        #pragma unroll
        for (int mi = 0; mi < 4; mi++){
            #pragma unroll
            for (int r = 0; r < 4; r++)
                att1[(size_t)(r0 + mi*16 + r)*NA + col] = f2bu(acc[mi][ni][r] + eb);
        }
    }
}

// Y = hsb(padded 1280) @ clsw(padded 10112)^T + cls_b, masked -> yout (B,T,V)
__global__ void k_gemm_cls(const unsigned short* __restrict__ hsb,
                           const unsigned short* __restrict__ clsw,
                           const float* __restrict__ cls_b,
                           const int* __restrict__ lengths,
                           float* __restrict__ yout){
    f32x4 acc[4][4] = {};
    int brow = blockIdx.x*128, bcol = blockIdx.y*128;
    gemm128<NH>(hsb, clsw, brow, bcol, acc);
    int w = threadIdx.x >> 6, l = threadIdx.x & 63;
    int wr = (w >> 1) * 64, wc = (w & 1) * 64;
    int r0 = brow + wr + (l >> 4)*4;
    int c0 = bcol + wc + (l & 15);
    #pragma unroll
    for (int ni = 0; ni < 4; ni++){
        int col = c0 + ni*16;
        if (col >= NV) continue;
        float cb = cls_b[col];
        #pragma unroll
        for (int mi = 0; mi < 4; mi++){
            #pragma unroll
            for (int r = 0; r < 4; r++){
                int grow = r0 + mi*16 + r;
                if (grow >= NT*64) continue;
                int t = grow >> 6, bb = grow & 63;
                int active = t < (lengths[bb] - 1);
                yout[((size_t)bb*NT + t)*NV + col] = active ? (acc[mi][ni][r] + cb) : 0.f;
            }
        }
    }
}

// ---------------- per-step kernels ----------------

// hp[b][0:512] = h@dec_w^T ; hp[b][512:2560] = h@f_beta_w^T  (biases added later)
__global__ void k_hproj(const unsigned short* __restrict__ hbf,
                        const unsigned short* __restrict__ hwb,
                        float* __restrict__ hp){
    int w = threadIdx.x >> 6, l = threadIdx.x & 63;
    int nt = blockIdx.x;                   // 0..159
    int row = 16*w + (l & 15);
    int col = nt*16 + (l & 15);
    int kg = (l >> 4) * 8;
    f32x4 acc = {};
    for (int k0 = 0; k0 < NH; k0 += 32){
        bf16x8 af = *(const bf16x8*)(hbf + row*NH + k0 + kg);
        bf16x8 bv = *(const bf16x8*)(hwb + col*NH + k0 + kg);
        acc = __builtin_amdgcn_mfma_f32_16x16x32_bf16(af, bv, acc, 0, 0, 0);
    }
    int r0 = 16*w + (l >> 4)*4;
    #pragma unroll
    for (int r = 0; r < 4; r++)
        hp[(r0 + r)*2560 + col] = acc[r];
}

// e scores; also (pc==0) fill xh emb part + h part
__global__ void k_e(const unsigned short* __restrict__ att1,
                    const float* __restrict__ hp, const float* __restrict__ dec_b,
                    const float* __restrict__ att_w, const float* __restrict__ att_b,
                    const float* __restrict__ emb, const int* __restrict__ captions,
                    const unsigned short* __restrict__ hbf,
                    unsigned short* __restrict__ xh, float* __restrict__ ews, int t){
    __shared__ float at2[NA];
    __shared__ float aw[NA];
    int b = blockIdx.x >> 2, pc = blockIdx.x & 3;
    int tid = threadIdx.x;
    for (int j = tid; j < NA; j += 256){
        at2[j] = hp[b*2560 + j] + dec_b[j];
        aw[j]  = att_w[j];
    }
    if (pc == 0){
        int cap = captions[b*20 + t];
        for (int k = tid; k < NE; k += 256) xh[b*NKX + k] = f2bu(emb[cap*NE + k]);
        for (int j = tid; j < NH; j += 256) xh[b*NKX + 2560 + j] = hbf[b*NH + j];
    }
    __syncthreads();
    int pl = tid >> 2, q = tid & 3;
    if (pl < 49){
        int p = pc*49 + pl;
        const unsigned short* arow = att1 + ((size_t)(b*NP + p))*NA + q*128;
        float s = 0.f;
        for (int a0 = 0; a0 < 128; a0 += 8){
            bf16x8 v = *(const bf16x8*)(arow + a0);
            #pragma unroll
            for (int e = 0; e < 8; e++){
                int a = q*128 + a0 + e;
                float x = b2f(v[e]) + at2[a];
                s += fmaxf(x, 0.f) * aw[a];
            }
        }
        s += __shfl_xor(s, 1);
        s += __shfl_xor(s, 2);
        if (q == 0) ews[b*NP + p] = s + att_b[0];
    }
}

// softmax(e) per b (redundant per dchunk), awe = alpha@feats via ftr, gate*awe -> xh
__global__ void k_awe(const float* __restrict__ ews, const unsigned short* __restrict__ ftr,
                      const float* __restrict__ hp, const float* __restrict__ f_beta_b,
                      const int* __restrict__ lengths,
                      unsigned short* __restrict__ xh, float* __restrict__ alphas_out, int t){
    __shared__ float al[PP];
    __shared__ float red[256];
    int dc = blockIdx.x;   // 0..7
    int b  = blockIdx.y;   // 0..63
    int tid = threadIdx.x;
    float v = (tid < NP) ? ews[b*NP + tid] : -1e30f;
    red[tid] = v; __syncthreads();
    for (int s = 128; s > 0; s >>= 1){ if (tid < s) red[tid] = fmaxf(red[tid], red[tid+s]); __syncthreads(); }
    float m = red[0]; __syncthreads();
    float ev = (tid < NP) ? __expf(v - m) : 0.f;
    red[tid] = ev; __syncthreads();
    for (int s = 128; s > 0; s >>= 1){ if (tid < s) red[tid] += red[tid+s]; __syncthreads(); }
    float inv = 1.f / red[0];
    if (tid < NP) al[tid] = ev * inv;
    if (tid >= NP && tid < PP) al[tid] = 0.f;
    __syncthreads();
    if (dc == 0 && tid < NP){
        int active = t < (lengths[b] - 1);
        alphas_out[((size_t)b*NT + t)*NP + tid] = active ? al[tid] : 0.f;
    }
    int d = dc*256 + tid;
    const unsigned short* fr = ftr + ((size_t)(b*ND + d))*PP;
    float a0 = 0.f, a1 = 0.f, a2 = 0.f, a3 = 0.f;
    #pragma unroll
    for (int c = 0; c < 25; c++){
        bf16x8 vv = *(const bf16x8*)(fr + c*8);
        float* accp = (c & 3) == 0 ? &a0 : (c & 3) == 1 ? &a1 : (c & 3) == 2 ? &a2 : &a3;
        float s = 0.f;
        #pragma unroll
        for (int j = 0; j < 8; j++) s += al[c*8 + j] * b2f(vv[j]);
        *accp += s;
    }
    float acc = (a0 + a1) + (a2 + a3);
    float g = sigm(hp[b*2560 + 512 + d] + f_beta_b[d]);
    xh[b*NKX + 512 + d] = f2bu(g * acc);
}

// gates partials: part[s][b][j] = sum over k in [s*384,(s+1)*384) of xh[b][k]*wcat[j][k]
__global__ void k_gates(const unsigned short* __restrict__ xh,
                        const unsigned short* __restrict__ wcat,
                        float* __restrict__ part){
    int w = threadIdx.x >> 6, l = threadIdx.x & 63;
    int nt = blockIdx.x;   // 0..127
    int s  = blockIdx.y;   // 0..7
    int row = 16*w + (l & 15);
    int col = nt*16 + (l & 15);
    int kg = (l >> 4) * 8;
    int kbase = s*384;
    f32x4 acc = {};
    for (int k0 = 0; k0 < 384; k0 += 32){
        bf16x8 af = *(const bf16x8*)(xh + row*NKX + kbase + k0 + kg);
        bf16x8 bv = *(const bf16x8*)(wcat + col*NKX + kbase + k0 + kg);
        acc = __builtin_amdgcn_mfma_f32_16x16x32_bf16(af, bv, acc, 0, 0, 0);
    }
    int r0 = 16*w + (l >> 4)*4;
    #pragma unroll
    for (int r = 0; r < 4; r++)
        part[(s*64 + r0 + r)*2048 + col] = acc[r];
}

// LSTM pointwise for step t-1 (t in 1..19)
__global__ void k_lstm(const float* __restrict__ part,
                       const float* __restrict__ b_ih, const float* __restrict__ b_hh,
                       float* __restrict__ cst, unsigned short* __restrict__ hbf,
                       unsigned short* __restrict__ hsb, int t){
    int idx = blockIdx.x*256 + threadIdx.x;
    int b = idx >> 9, j = idx & 511;
    float gi = b_ih[j]        + b_hh[j];
    float gf = b_ih[512 + j]  + b_hh[512 + j];
    float gg = b_ih[1024 + j] + b_hh[1024 + j];
    float go = b_ih[1536 + j] + b_hh[1536 + j];
    #pragma unroll
    for (int s = 0; s < 8; s++){
        const float* pb = part + (s*64 + b)*2048;
        gi += pb[j]; gf += pb[512 + j]; gg += pb[1024 + j]; go += pb[1536 + j];
    }
    float c = cst[b*NH + j];
    float c2 = sigm(gf)*c + sigm(gi)*tanhf(gg);
    float h2 = sigm(go)*tanhf(c2);
    cst[b*NH + j] = c2;
    unsigned short hb16 = f2bu(h2);
    hbf[b*NH + j] = hb16;
    hsb[((t - 1)*64 + b)*NH + j] = hb16;
}

// ---------------- launch ----------------

extern "C" void kernel_launch(void* const* d_in, const int* in_sizes, int n_in,
                              void* d_out, int out_size, void* d_ws, size_t ws_size,
                              hipStream_t stream){
    const float* features = (const float*)d_in[0];
    const int*   captions = (const int*)d_in[1];
    const int*   lengths  = (const int*)d_in[2];
    const float* emb      = (const float*)d_in[3];
    const float* W_ih     = (const float*)d_in[4];
    const float* b_ih     = (const float*)d_in[5];
    const float* W_hh     = (const float*)d_in[6];
    const float* b_hh     = (const float*)d_in[7];
    const float* h_fc_w   = (const float*)d_in[8];
    const float* h_fc_b   = (const float*)d_in[9];
    const float* c_fc_w   = (const float*)d_in[10];
    const float* c_fc_b   = (const float*)d_in[11];
    const float* f_beta_w = (const float*)d_in[12];
    const float* f_beta_b = (const float*)d_in[13];
    const float* cls_w    = (const float*)d_in[14];
    const float* cls_b    = (const float*)d_in[15];
    const float* enc_w    = (const float*)d_in[16];
    const float* enc_b    = (const float*)d_in[17];
    const float* dec_w    = (const float*)d_in[18];
    const float* dec_b    = (const float*)d_in[19];
    const float* att_w    = (const float*)d_in[20];
    const float* att_b    = (const float*)d_in[21];

    char* w = (char*)d_ws;
    size_t off = 0;
    auto alloc = [&](size_t bytes)->char*{
        char* p = w + off;
        off += (bytes + 255) & ~(size_t)255;
        return p;
    };
    unsigned short* fbf   = (unsigned short*)alloc((size_t)NROW*ND*2);
    unsigned short* ftr   = (unsigned short*)alloc((size_t)NB*ND*PP*2);
    unsigned short* att1  = (unsigned short*)alloc((size_t)NROW*NA*2);
    unsigned short* encwb = (unsigned short*)alloc((size_t)NA*ND*2);
    unsigned short* hwb   = (unsigned short*)alloc((size_t)2560*NH*2);
    unsigned short* wcat  = (unsigned short*)alloc((size_t)2048*NKX*2);
    unsigned short* clswb = (unsigned short*)alloc((size_t)NVP*NH*2);
    unsigned short* hsb   = (unsigned short*)alloc((size_t)MROW*NH*2);
    unsigned short* hbf   = (unsigned short*)alloc((size_t)64*NH*2);
    unsigned short* xh    = (unsigned short*)alloc((size_t)64*NKX*2);
    float* meanf = (float*)alloc((size_t)64*ND*4);
    float* cst   = (float*)alloc((size_t)64*NH*4);
    float* hp    = (float*)alloc((size_t)64*2560*4);
    float* ews   = (float*)alloc((size_t)64*NP*4);
    float* part  = (float*)alloc((size_t)8*64*2048*4);

    float* yout = (float*)d_out;
    float* alphas_out = yout + (size_t)NB*NT*NV;

    // setup
    k_tr<<<dim3(32, 64), 256, 0, stream>>>(features, fbf, ftr, meanf);
    k_cast4<<<1024, 256, 0, stream>>>((const float4*)enc_w, (ushort4*)encwb, NA*ND/4);
    k_cast4<<<256, 256, 0, stream>>>((const float4*)dec_w, (ushort4*)hwb, 512*512/4);
    k_cast4<<<1024, 256, 0, stream>>>((const float4*)f_beta_w, (ushort4*)(hwb + 512*512), 2048*512/4);
    k_wcat<<<dim3(2048, 12), 256, 0, stream>>>(W_ih, W_hh, wcat);
    k_cast4<<<2048, 256, 0, stream>>>((const float4*)cls_w, (ushort4*)clswb, NV*NH/4);
    hipMemsetAsync(clswb + (size_t)NV*NH, 0, (size_t)(NVP - NV)*NH*2, stream);
    hipMemsetAsync(hsb + (size_t)NT*64*NH, 0, (size_t)(MROW - NT*64)*NH*2, stream);
    k_hc0<<<dim3(128, 2), 256, 0, stream>>>(meanf, h_fc_w, h_fc_b, c_fc_w, c_fc_b, hbf, cst);
    k_gemm_att1<<<dim3(98, 4), 256, 0, stream>>>(fbf, encwb, enc_b, att1);

    for (int t = 0; t < NT; t++){
        if (t > 0)
            k_lstm<<<128, 256, 0, stream>>>(part, b_ih, b_hh, cst, hbf, hsb, t);
        k_hproj<<<160, 256, 0, stream>>>(hbf, hwb, hp);
        k_e<<<256, 256, 0, stream>>>(att1, hp, dec_b, att_w, att_b, emb, captions, hbf, xh, ews, t);
        k_awe<<<dim3(8, 64), 256, 0, stream>>>(ews, ftr, hp, f_beta_b, lengths, xh, alphas_out, t);
        k_gates<<<dim3(128, 8), 256, 0, stream>>>(xh, wcat, part);
    }
    k_lstm<<<128, 256, 0, stream>>>(part, b_ih, b_hh, cst, hbf, hsb, NT);
    k_gemm_cls<<<dim3(10, 79), 256, 0, stream>>>(hsb, clswb, cls_b, lengths, yout);
}